// Round 1
// baseline (366.097 us; speedup 1.0000x reference)
//
#include <hip/hip_runtime.h>
#include <stdint.h>

#define N_COLS 524288
#define N_PRIMES 168
#define COLS_PER_THREAD 4
#define BLOCK 256

// primes below 1000 — compile-time constants so % p lowers to magic-multiply
static constexpr uint32_t PRIMES[N_PRIMES] = {
      2,   3,   5,   7,  11,  13,  17,  19,  23,  29,
     31,  37,  41,  43,  47,  53,  59,  61,  67,  71,
     73,  79,  83,  89,  97, 101, 103, 107, 109, 113,
    127, 131, 137, 139, 149, 151, 157, 163, 167, 173,
    179, 181, 191, 193, 197, 199, 211, 223, 227, 229,
    233, 239, 241, 251, 257, 263, 269, 271, 277, 281,
    283, 293, 307, 311, 313, 317, 331, 337, 347, 349,
    353, 359, 367, 373, 379, 383, 389, 397, 401, 409,
    419, 421, 431, 433, 439, 443, 449, 457, 461, 463,
    467, 479, 487, 491, 499, 503, 509, 521, 523, 541,
    547, 557, 563, 569, 571, 577, 587, 593, 599, 601,
    607, 613, 617, 619, 631, 641, 643, 647, 653, 659,
    661, 673, 677, 683, 691, 701, 709, 719, 727, 733,
    739, 743, 751, 757, 761, 769, 773, 787, 797, 809,
    811, 821, 823, 827, 829, 839, 853, 857, 859, 863,
    877, 881, 883, 887, 907, 911, 919, 929, 937, 941,
    947, 953, 967, 971, 977, 983, 991, 997
};

// Fused kernel: each thread owns 4 consecutive columns. It computes the
// prime-mask weight/bias for those 4 columns ONCE (into registers), then
// streams all B batch rows with float4 loads/stores (HBM-bound phase).
__global__ __launch_bounds__(BLOCK) void bwl_prime_fused(
    const float* __restrict__ x,
    const float* __restrict__ kern,
    const float* __restrict__ bias,
    float* __restrict__ out,
    int B)
{
    const int tid  = blockIdx.x * BLOCK + threadIdx.x;
    const uint32_t col0 = (uint32_t)tid * COLS_PER_THREAD;

    // ---- Phase 1: mask computation (L1/L2 gather-bound, done once) ----
    float w0 = 0.f, w1 = 0.f, w2 = 0.f, w3 = 0.f;
    float b0 = 0.f, b1 = 0.f, b2 = 0.f, b3 = 0.f;
#pragma unroll
    for (int i = 0; i < N_PRIMES; ++i) {
        const uint32_t p = PRIMES[i];       // compile-time constant
        const int rowoff = i * 1000;        // compile-time constant
        uint32_t m0 = col0 % p;             // magic-multiply
        uint32_t m1 = m0 + 1; if (m1 == p) m1 = 0;
        uint32_t m2 = m1 + 1; if (m2 == p) m2 = 0;
        uint32_t m3 = m2 + 1; if (m3 == p) m3 = 0;
        w0 += kern[rowoff + (int)m0];  b0 += bias[rowoff + (int)m0];
        w1 += kern[rowoff + (int)m1];  b1 += bias[rowoff + (int)m1];
        w2 += kern[rowoff + (int)m2];  b2 += bias[rowoff + (int)m2];
        w3 += kern[rowoff + (int)m3];  b3 += bias[rowoff + (int)m3];
    }

    // ---- Phase 2: stream the batch (HBM-bound) ----
    const float4* __restrict__ x4 = (const float4*)x;
    float4* __restrict__ o4 = (float4*)out;
    const int stride4 = N_COLS / 4;   // 131072 float4 per row
    const int cidx = tid;             // float4 column-group index

#pragma unroll 4
    for (int r = 0; r < B; ++r) {
        const size_t off = (size_t)r * stride4 + cidx;
        float4 xv = x4[off];
        float4 ov;
        ov.x = fmaf(xv.x, w0, b0);
        ov.y = fmaf(xv.y, w1, b1);
        ov.z = fmaf(xv.z, w2, b2);
        ov.w = fmaf(xv.w, w3, b3);
        o4[off] = ov;
    }
}

extern "C" void kernel_launch(void* const* d_in, const int* in_sizes, int n_in,
                              void* d_out, int out_size, void* d_ws, size_t ws_size,
                              hipStream_t stream) {
    const float* x    = (const float*)d_in[0];
    const float* kern = (const float*)d_in[1];
    const float* bias = (const float*)d_in[2];
    float* out = (float*)d_out;

    const int B = in_sizes[0] / N_COLS;   // 64
    const int grid = N_COLS / (BLOCK * COLS_PER_THREAD);  // 512 blocks

    bwl_prime_fused<<<grid, BLOCK, 0, stream>>>(x, kern, bias, out, B);
}